// Round 4
// baseline (150.694 us; speedup 1.0000x reference)
//
#include <hip/hip_runtime.h>
#include <math.h>

// Problem constants
#define TT   4096
#define NBB  32
#define NUU  64
#define NHH  256
#define HH   128
#define NYY  64
// Chunking: 512 chunks of 8 steps; carry hierarchy: 16 supers x 32 chunks
#define LCH  8
#define CCH  512
#define SEGN 16
#define CPS  32

#define PI_HALF 1.5707963267948966f

typedef float  f32x16 __attribute__((ext_vector_type(16)));
typedef __bf16 bf16x8 __attribute__((ext_vector_type(8)));
typedef __bf16 bf16x2 __attribute__((ext_vector_type(2)));
typedef unsigned int uint4v __attribute__((ext_vector_type(4)));

// MFMA 32x32 C/D layout: row = (r&3) + 8*(r>>2) + 4*(lane>>5), col = lane&31
__device__ inline int crow(int r, int lane) { return (r & 3) + 8 * (r >> 2) + 4 * (lane >> 5); }
__device__ inline bf16x8 ldfrag(const unsigned short* p) {
    return __builtin_bit_cast(bf16x8, *(const uint4v*)p);
}
__device__ inline void store_cvt(unsigned short* dst, float4 f0, float4 f1, float4 f2, float4 f3) {
    bf16x8 p0, p1;
    p0[0]=(__bf16)f0.x; p0[1]=(__bf16)f0.y; p0[2]=(__bf16)f0.z; p0[3]=(__bf16)f0.w;
    p0[4]=(__bf16)f1.x; p0[5]=(__bf16)f1.y; p0[6]=(__bf16)f1.z; p0[7]=(__bf16)f1.w;
    p1[0]=(__bf16)f2.x; p1[1]=(__bf16)f2.y; p1[2]=(__bf16)f2.z; p1[3]=(__bf16)f2.w;
    p1[4]=(__bf16)f3.x; p1[5]=(__bf16)f3.y; p1[6]=(__bf16)f3.z; p1[7]=(__bf16)f3.w;
    *(bf16x8*)dst       = p0;
    *(bf16x8*)(dst + 8) = p1;
}

// ---------------------------------------------------------------------------
// Prep: x0 pairs + wave-coalesced swizzled fragment arrays.
// Bsw[(((w*2+nt)*4+kk)*64 + lane)*8 + e] = bf16(B[(nt*128 + w*32 + l31)*64 + kk*16 + kh*8 + e])
// Wsw[((ntl*16+kk)*64 + lane)*8 + e]    = bf16(Wperm[ntl*32+l31][kk*16+kh*8+e]),
//   Wperm[y][2j] = W[y][j], Wperm[y][2j+1] = W[y][j+128]
// ---------------------------------------------------------------------------
__global__ __launch_bounds__(256) void k_prep(
    const float* __restrict__ B, const float* __restrict__ W,
    const float* __restrict__ y0, const float* __restrict__ Wy2x,
    const float* __restrict__ by2x,
    unsigned short* __restrict__ Bsw, unsigned short* __restrict__ Wsw,
    float2* __restrict__ x0p)
{
    int bx = blockIdx.x, tid = threadIdx.x;
    if (bx < 32) {
        if (tid < HH) {
            int b = bx, ch = tid;
            float xr = by2x[ch], xi = by2x[ch + HH];
            for (int y = 0; y < NYY; ++y) {
                float v = y0[b * NYY + y];
                xr += v * Wy2x[ch * NYY + y];
                xi += v * Wy2x[(ch + HH) * NYY + y];
            }
            x0p[b * HH + ch] = make_float2(xr, xi);
        }
    } else {
        int i = (bx - 32) * 256 + tid;            // 0..16383
        {   // Bsw
            int e = i & 7, lane = (i >> 3) & 63, kk = (i >> 9) & 3, nt = (i >> 11) & 1, w = i >> 12;
            int l31 = lane & 31, kh = lane >> 5;
            Bsw[i] = __builtin_bit_cast(unsigned short,
                     (__bf16)B[(nt * HH + w * 32 + l31) * NUU + kk * 16 + kh * 8 + e]);
        }
        {   // Wsw
            int e = i & 7, lane = (i >> 3) & 63, kk = (i >> 9) & 15, ntl = i >> 13;
            int l31 = lane & 31, kh = lane >> 5;
            int kperm = kk * 16 + kh * 8 + e;
            Wsw[i] = __builtin_bit_cast(unsigned short,
                     (__bf16)W[(ntl * 32 + l31) * NHH + (kperm & 1) * HH + (kperm >> 1)]);
        }
    }
}

// ---------------------------------------------------------------------------
// Pass 1: per-chunk (L=8) local end state. B-frags in registers (coalesced
// swizzled loads), double-buffered sU, ONE barrier per sub.
// ---------------------------------------------------------------------------
__global__ __launch_bounds__(256, 2) void k_pass1(
    const float* __restrict__ U, const unsigned short* __restrict__ Bsw,
    const float* __restrict__ lre, const float* __restrict__ lim,
    float2* __restrict__ E)
{
    __shared__ __align__(16) unsigned short sU[2][64 * 72];   // 18 KB

    const int tid = threadIdx.x, w = tid >> 6, lane = tid & 63;
    const int l31 = lane & 31, kh = lane >> 5;
    const int c = blockIdx.x;
    const int ch = w * 32 + l31;
    const int srow = tid >> 2, sus = (tid & 3) * 16;   // staging row / u-offset
    const int sb = srow & 31, st_off = srow >> 5;      // staging batch / t-offset

    // B fragments (registers, coalesced loads)
    bf16x8 bf[2][4];
#pragma unroll
    for (int nt = 0; nt < 2; ++nt)
#pragma unroll
        for (int kk = 0; kk < 4; ++kk)
            bf[nt][kk] = ldfrag(&Bsw[((((w * 2 + nt) * 4 + kk) * 64) + lane) * 8]);

    float rr = expf(-fabsf(lre[ch])), th = PI_HALF * lim[ch];
    float lr = rr * cosf(th), li = rr * sinf(th);

    // Stage sub 0 into buffer 0
    {
        const float4* s = (const float4*)(U + ((size_t)(c * LCH + st_off) * NBB + sb) * NUU + sus);
        store_cvt(&sU[0][srow * 72 + sus], s[0], s[1], s[2], s[3]);
    }
    float zr[16], zi[16];
#pragma unroll
    for (int r = 0; r < 16; ++r) { zr[r] = 0.f; zi[r] = 0.f; }
    __syncthreads();

    for (int sub = 0; sub < 4; ++sub) {
        const int cur = sub & 1;
        // Prefetch U(sub+1) into registers (issued early; consumed at epoch end)
        int tld = c * LCH + ((sub < 3) ? (sub + 1) * 2 : 0) + st_off;
        const float4* s = (const float4*)(U + ((size_t)tld * NBB + sb) * NUU + sus);
        float4 f0 = s[0], f1 = s[1], f2 = s[2], f3 = s[3];

        // Bu MFMA from sU[cur]
        f32x16 acc[2][2];
#pragma unroll
        for (int mt = 0; mt < 2; ++mt)
#pragma unroll
            for (int nt = 0; nt < 2; ++nt)
#pragma unroll
                for (int r = 0; r < 16; ++r) acc[mt][nt][r] = 0.f;
#pragma unroll
        for (int kk = 0; kk < 4; ++kk) {
            bf16x8 a0 = ldfrag(&sU[cur][(l31)      * 72 + kk * 16 + kh * 8]);
            bf16x8 a1 = ldfrag(&sU[cur][(32 + l31) * 72 + kk * 16 + kh * 8]);
            acc[0][0] = __builtin_amdgcn_mfma_f32_32x32x16_bf16(a0, bf[0][kk], acc[0][0], 0, 0, 0);
            acc[0][1] = __builtin_amdgcn_mfma_f32_32x32x16_bf16(a0, bf[1][kk], acc[0][1], 0, 0, 0);
            acc[1][0] = __builtin_amdgcn_mfma_f32_32x32x16_bf16(a1, bf[0][kk], acc[1][0], 0, 0, 0);
            acc[1][1] = __builtin_amdgcn_mfma_f32_32x32x16_bf16(a1, bf[1][kk], acc[1][1], 0, 0, 0);
        }
        // Scan (2 time steps)
#pragma unroll
        for (int mt = 0; mt < 2; ++mt)
#pragma unroll
            for (int r = 0; r < 16; ++r) {
                float t0 = fmaf(lr, zr[r], acc[mt][0][r]); t0 = fmaf(-li, zi[r], t0);
                float t1 = fmaf(li, zr[r], acc[mt][1][r]); t1 = fmaf(lr, zi[r], t1);
                zr[r] = t0; zi[r] = t1;
            }
        // Write staged U(sub+1) to the other buffer
        store_cvt(&sU[cur ^ 1][srow * 72 + sus], f0, f1, f2, f3);
        __syncthreads();
    }

#pragma unroll
    for (int r = 0; r < 16; ++r)
        E[(size_t)c * 4096 + crow(r, lane) * HH + ch] = make_float2(zr[r], zi[r]);
}

// ---------------------------------------------------------------------------
// Carry hierarchy (unchanged). chain = b*128 + ch.
// ---------------------------------------------------------------------------
__global__ __launch_bounds__(256) void k_cseg(
    const float* __restrict__ lre, const float* __restrict__ lim,
    const float2* __restrict__ E, float2* __restrict__ Esup)
{
    int g = blockIdx.x * 256 + threadIdx.x;
    int chain = g & 4095, seg = g >> 12, ch = chain & 127;
    float rr = expf(-fabsf(lre[ch])), th = PI_HALF * lim[ch];
    float pr = rr * cosf(th), pi = rr * sinf(th);
#pragma unroll
    for (int s = 0; s < 3; ++s) { float nr = pr*pr - pi*pi, ni = 2.f*pr*pi; pr = nr; pi = ni; }
    float sr = 0.f, si = 0.f;
#pragma unroll 8
    for (int j = 0; j < CPS; ++j) {
        float2 e = E[((size_t)seg * CPS + j) * 4096 + chain];
        float nr = pr * sr - pi * si + e.x;
        float ni = pi * sr + pr * si + e.y;
        sr = nr; si = ni;
    }
    Esup[(size_t)seg * 4096 + chain] = make_float2(sr, si);
}

__global__ __launch_bounds__(256) void k_csup(
    const float* __restrict__ lre, const float* __restrict__ lim,
    const float2* __restrict__ x0p, const float2* __restrict__ Esup,
    float2* __restrict__ CarrySup)
{
    int chain = blockIdx.x * 256 + threadIdx.x;
    int ch = chain & 127;
    float rr = expf(-fabsf(lre[ch])), th = PI_HALF * lim[ch];
    float pr = rr * cosf(th), pi = rr * sinf(th);
#pragma unroll
    for (int s = 0; s < 8; ++s) { float nr = pr*pr - pi*pi, ni = 2.f*pr*pi; pr = nr; pi = ni; }
    float2 c0 = x0p[chain];
    float cr = c0.x, ci = c0.y;
#pragma unroll
    for (int s = 0; s < SEGN; ++s) {
        CarrySup[(size_t)s * 4096 + chain] = make_float2(cr, ci);
        float2 e = Esup[(size_t)s * 4096 + chain];
        float nr = pr * cr - pi * ci + e.x;
        float ni = pi * cr + pr * ci + e.y;
        cr = nr; ci = ni;
    }
}

__global__ __launch_bounds__(256) void k_cexp(
    const float* __restrict__ lre, const float* __restrict__ lim,
    const float2* __restrict__ E, const float2* __restrict__ CarrySup,
    float2* __restrict__ Carry)
{
    int g = blockIdx.x * 256 + threadIdx.x;
    int chain = g & 4095, seg = g >> 12, ch = chain & 127;
    float rr = expf(-fabsf(lre[ch])), th = PI_HALF * lim[ch];
    float pr = rr * cosf(th), pi = rr * sinf(th);
#pragma unroll
    for (int s = 0; s < 3; ++s) { float nr = pr*pr - pi*pi, ni = 2.f*pr*pi; pr = nr; pi = ni; }
    float2 cc = CarrySup[(size_t)seg * 4096 + chain];
    float cr = cc.x, ci = cc.y;
#pragma unroll 8
    for (int j = 0; j < CPS; ++j) {
        size_t idx = ((size_t)seg * CPS + j) * 4096 + chain;
        Carry[idx] = make_float2(cr, ci);
        float2 e = E[idx];
        float nr = pr * cr - pi * ci + e.x;
        float ni = pi * cr + pr * ci + e.y;
        cr = nr; ci = ni;
    }
}

// ---------------------------------------------------------------------------
// Pass 2: seeded scan + fused output GEMM. W fragments in REGISTERS (16x16B,
// coalesced swizzled loads), B fragments in registers, double-buffered sU.
// Per sub: [prefetch U; Bu MFMA; scan; dump sX][B][out-GEMM; stage sU][B]
// ---------------------------------------------------------------------------
__global__ __launch_bounds__(256, 2) void k_pass2(
    const float* __restrict__ U, const unsigned short* __restrict__ Bsw,
    const unsigned short* __restrict__ Wsw,
    const float* __restrict__ lre, const float* __restrict__ lim,
    const float* __restrict__ bx2y,
    const float2* __restrict__ Carry, float* __restrict__ Y)
{
    __shared__ __align__(16) unsigned short sU[2][64 * 72];   // 18 KB
    __shared__ __align__(16) unsigned short sX[64 * 264];     // 33 KB

    const int tid = threadIdx.x, w = tid >> 6, lane = tid & 63;
    const int l31 = lane & 31, kh = lane >> 5;
    const int c = blockIdx.x;
    const int ch = w * 32 + l31;
    const int mtile = w & 1, ntile = w >> 1;
    const int srow = tid >> 2, sus = (tid & 3) * 16;
    const int sb = srow & 31, st_off = srow >> 5;

    // Seed from Carry (issued early)
    float zr[16], zi[16];
#pragma unroll
    for (int r = 0; r < 16; ++r) {
        float2 v = Carry[(size_t)c * 4096 + crow(r, lane) * HH + ch];
        zr[r] = v.x; zi[r] = v.y;
    }

    // B + W fragments in registers (coalesced)
    bf16x8 bf[2][4];
#pragma unroll
    for (int nt = 0; nt < 2; ++nt)
#pragma unroll
        for (int kk = 0; kk < 4; ++kk)
            bf[nt][kk] = ldfrag(&Bsw[((((w * 2 + nt) * 4 + kk) * 64) + lane) * 8]);
    bf16x8 wf[16];
#pragma unroll
    for (int kk = 0; kk < 16; ++kk)
        wf[kk] = ldfrag(&Wsw[(((ntile * 16 + kk) * 64) + lane) * 8]);

    float rr = expf(-fabsf(lre[ch])), th = PI_HALF * lim[ch];
    float lr = rr * cosf(th), li = rr * sinf(th);
    float ybias = bx2y[ntile * 32 + l31];

    // Stage sub 0
    {
        const float4* s = (const float4*)(U + ((size_t)(c * LCH + st_off) * NBB + sb) * NUU + sus);
        store_cvt(&sU[0][srow * 72 + sus], s[0], s[1], s[2], s[3]);
    }
    __syncthreads();

    for (int sub = 0; sub < 4; ++sub) {
        const int cur = sub & 1;
        // Prefetch U(sub+1) into registers
        int tld = c * LCH + ((sub < 3) ? (sub + 1) * 2 : 0) + st_off;
        const float4* s = (const float4*)(U + ((size_t)tld * NBB + sb) * NUU + sus);
        float4 f0 = s[0], f1 = s[1], f2 = s[2], f3 = s[3];

        // Bu MFMA from sU[cur]
        f32x16 acc[2][2];
#pragma unroll
        for (int mt = 0; mt < 2; ++mt)
#pragma unroll
            for (int nt = 0; nt < 2; ++nt)
#pragma unroll
                for (int r = 0; r < 16; ++r) acc[mt][nt][r] = 0.f;
#pragma unroll
        for (int kk = 0; kk < 4; ++kk) {
            bf16x8 a0 = ldfrag(&sU[cur][(l31)      * 72 + kk * 16 + kh * 8]);
            bf16x8 a1 = ldfrag(&sU[cur][(32 + l31) * 72 + kk * 16 + kh * 8]);
            acc[0][0] = __builtin_amdgcn_mfma_f32_32x32x16_bf16(a0, bf[0][kk], acc[0][0], 0, 0, 0);
            acc[0][1] = __builtin_amdgcn_mfma_f32_32x32x16_bf16(a0, bf[1][kk], acc[0][1], 0, 0, 0);
            acc[1][0] = __builtin_amdgcn_mfma_f32_32x32x16_bf16(a1, bf[0][kk], acc[1][0], 0, 0, 0);
            acc[1][1] = __builtin_amdgcn_mfma_f32_32x32x16_bf16(a1, bf[1][kk], acc[1][1], 0, 0, 0);
        }

        // Scan + interleaved-pair dump to sX (cols 2j=re_j, 2j+1=im_j)
#pragma unroll
        for (int mt = 0; mt < 2; ++mt)
#pragma unroll
            for (int r = 0; r < 16; ++r) {
                float t0 = fmaf(lr, zr[r], acc[mt][0][r]); t0 = fmaf(-li, zi[r], t0);
                float t1 = fmaf(li, zr[r], acc[mt][1][r]); t1 = fmaf(lr, zi[r], t1);
                zr[r] = t0; zi[r] = t1;
                bf16x2 pv; pv[0] = (__bf16)t0; pv[1] = (__bf16)t1;
                *(bf16x2*)&sX[(mt * 32 + crow(r, lane)) * 264 + w * 64 + 2 * l31] = pv;
            }
        __syncthreads();   // sX ready

        // Out-GEMM: wave (mtile,ntile); W from registers; 2 chains
        f32x16 ya0, ya1;
#pragma unroll
        for (int r = 0; r < 16; ++r) { ya0[r] = 0.f; ya1[r] = 0.f; }
#pragma unroll
        for (int kk = 0; kk < 16; kk += 2) {
            bf16x8 xa0 = ldfrag(&sX[(mtile * 32 + l31) * 264 + kk * 16 + kh * 8]);
            bf16x8 xa1 = ldfrag(&sX[(mtile * 32 + l31) * 264 + (kk + 1) * 16 + kh * 8]);
            ya0 = __builtin_amdgcn_mfma_f32_32x32x16_bf16(xa0, wf[kk],     ya0, 0, 0, 0);
            ya1 = __builtin_amdgcn_mfma_f32_32x32x16_bf16(xa1, wf[kk + 1], ya1, 0, 0, 0);
        }
        int t = c * LCH + sub * 2 + mtile;
#pragma unroll
        for (int r = 0; r < 16; ++r)
            Y[((size_t)t * NBB + crow(r, lane)) * NYY + ntile * 32 + l31] = ya0[r] + ya1[r] + ybias;

        // Write staged U(sub+1) to the other buffer
        store_cvt(&sU[cur ^ 1][srow * 72 + sus], f0, f1, f2, f3);
        __syncthreads();   // sU(sub+1) ready; sX readers done
    }
}

// ---------------------------------------------------------------------------
extern "C" void kernel_launch(void* const* d_in, const int* in_sizes, int n_in,
                              void* d_out, int out_size, void* d_ws, size_t ws_size,
                              hipStream_t stream) {
    const float* y0    = (const float*)d_in[0];
    const float* U     = (const float*)d_in[1];
    const float* lre   = (const float*)d_in[2];
    const float* lim   = (const float*)d_in[3];
    const float* B     = (const float*)d_in[4];
    const float* W_y2x = (const float*)d_in[5];
    const float* b_y2x = (const float*)d_in[6];
    const float* W_x2y = (const float*)d_in[7];
    const float* b_x2y = (const float*)d_in[8];
    float* Y = (float*)d_out;

    char* p = (char*)d_ws;
    float2* E        = (float2*)p; p += (size_t)CCH * 4096 * sizeof(float2);   // 16 MB
    float2* Carry    = (float2*)p; p += (size_t)CCH * 4096 * sizeof(float2);   // 16 MB
    float2* Esup     = (float2*)p; p += (size_t)SEGN * 4096 * sizeof(float2);  // 512 KB
    float2* CarrySup = (float2*)p; p += (size_t)SEGN * 4096 * sizeof(float2);  // 512 KB
    float2* x0p      = (float2*)p; p += (size_t)4096 * sizeof(float2);         // 32 KB
    unsigned short* Bsw = (unsigned short*)p; p += 16384 * sizeof(unsigned short);
    unsigned short* Wsw = (unsigned short*)p; p += 16384 * sizeof(unsigned short);

    k_prep <<<dim3(96),  dim3(256), 0, stream>>>(B, W_x2y, y0, W_y2x, b_y2x, Bsw, Wsw, x0p);
    k_pass1<<<dim3(CCH), dim3(256), 0, stream>>>(U, Bsw, lre, lim, E);
    k_cseg <<<dim3(256), dim3(256), 0, stream>>>(lre, lim, E, Esup);
    k_csup <<<dim3(16),  dim3(256), 0, stream>>>(lre, lim, x0p, Esup, CarrySup);
    k_cexp <<<dim3(256), dim3(256), 0, stream>>>(lre, lim, E, CarrySup, Carry);
    k_pass2<<<dim3(CCH), dim3(256), 0, stream>>>(U, Bsw, Wsw, lre, lim, b_x2y, Carry, Y);
}